// Round 10
// baseline (205.691 us; speedup 1.0000x reference)
//
#include <hip/hip_runtime.h>
#include <hip/hip_bf16.h>

using bf16 = __hip_bfloat16;
typedef __bf16 bf16x8 __attribute__((ext_vector_type(8)));
typedef short short4v __attribute__((ext_vector_type(4)));
typedef short short8v __attribute__((ext_vector_type(8)));
typedef float float4v __attribute__((ext_vector_type(4)));

#define DIM   768
#define NH    12
#define HD    64
#define SEQ   2048
#define BATCH 4
#define TOK   (BATCH * SEQ)   // 8192
// softmax scale * log2(e) folded into q at QKV epilogue (flash uses exp2)
#define SCALE_QL2E 0.18033688011112042f

#define NX  (TOK * DIM)        // 6291456
#define NWQ (3 * DIM * DIM)    // 1769472
#define NWP (DIM * DIM)        //  589824

__device__ __forceinline__ short f2bf(float f) {
  union { bf16 h; short s; } u;
  u.h = __float2bfloat16(f);
  return u.s;
}

// packed f32x2 -> bf16x2 (RNE), single HW instruction (T12 recipe;
// no builtin on gfx950).  Replaces the ~6-op software __float2bfloat16 path.
__device__ __forceinline__ unsigned cvtpk_bf16(float lo, float hi) {
  unsigned r;
  asm("v_cvt_pk_bf16_f32 %0, %1, %2" : "=v"(r) : "v"(lo), "v"(hi));
  return r;
}

union frag8 { short4v h[2]; short8v s; bf16x8 b; unsigned u[4]; };

// global(16B) -> LDS async DMA; LDS dest must be wave-uniform base + lane*16B
__device__ __forceinline__ void async_copy16(const bf16* g, short* l) {
  __builtin_amdgcn_global_load_lds(
      (const __attribute__((address_space(1))) unsigned int*)g,
      (__attribute__((address_space(3))) unsigned int*)l, 16, 0, 0);
}
// 4B variant (partial-row staging; dest = base + lane*4B)
__device__ __forceinline__ void async_copy4(const bf16* g, short* l) {
  __builtin_amdgcn_global_load_lds(
      (const __attribute__((address_space(1))) unsigned int*)g,
      (__attribute__((address_space(3))) unsigned int*)l, 4, 0, 0);
}

#define BARRIER __builtin_amdgcn_s_barrier()
#define LGKM0 asm volatile("s_waitcnt lgkmcnt(0)" ::: "memory")
#define VW0 asm volatile("s_waitcnt vmcnt(0)" ::: "memory")
#define NOSTG (void)0
#define NOVW  (void)0

// ---------------------------------------------------------------------------
// Kernel 0: f32 -> bf16 convert for x, w_qkv, w_proj (one fused launch)
// ---------------------------------------------------------------------------
__global__ void __launch_bounds__(256)
cvt3(const float* __restrict__ a, bf16* __restrict__ oa, long na,
     const float* __restrict__ b, bf16* __restrict__ ob, long nb,
     const float* __restrict__ c, bf16* __restrict__ oc, long nc) {
  const long i = ((long)blockIdx.x * 256 + threadIdx.x) * 8;
  const float* src; bf16* dst; long off;
  if (i < na)                { src = a; dst = oa; off = i; }
  else if (i < na + nb)      { src = b; dst = ob; off = i - na; }
  else if (i < na + nb + nc) { src = c; dst = oc; off = i - na - nb; }
  else return;
  const float4v x0 = *(const float4v*)(src + off);
  const float4v x1 = *(const float4v*)(src + off + 4);
  short8v r;
  r[0] = f2bf(x0[0]); r[1] = f2bf(x0[1]); r[2] = f2bf(x0[2]); r[3] = f2bf(x0[3]);
  r[4] = f2bf(x1[0]); r[5] = f2bf(x1[1]); r[6] = f2bf(x1[2]); r[7] = f2bf(x1[3]);
  *(short8v*)(dst + off) = r;
}

// ---------------------------------------------------------------------------
// Shared 128x128 bf16 GEMM main loop (m97 structure) — still used by gemm_proj
// ---------------------------------------------------------------------------
__device__ __forceinline__ void gemm_mainloop(const bf16* __restrict__ A,
                                              const bf16* __restrict__ B,
                                              short* As, short* Bs,
                                              float4v acc[4][4]) {
  const int t = threadIdx.x;
  const int w = t >> 6, l = t & 63, lr = l & 15, q = l >> 4;
  const int wr = ((w >> 1) << 6), wc = ((w & 1) << 6);

  const bf16* Ag = A + (t >> 2) * DIM + (t & 3) * 8;
  const bf16* Bg = B + (t >> 2) * DIM + (t & 3) * 8;

  for (int k0 = 0; k0 < DIM; k0 += 32) {
    __syncthreads();                       // previous tile's consumers done
    async_copy16(Ag,            &As[t * 8]);
    async_copy16(Ag + 64 * DIM, &As[2048 + t * 8]);
    async_copy16(Bg,            &Bs[t * 8]);
    async_copy16(Bg + 64 * DIM, &Bs[2048 + t * 8]);
    Ag += 32; Bg += 32;
    __syncthreads();                       // vmcnt(0) drain before barrier

    bf16x8 af[4], bfv[4];
#pragma unroll
    for (int i = 0; i < 4; ++i)
      af[i] = *(const bf16x8*)&As[(wr + i * 16 + lr) * 32 + q * 8];
#pragma unroll
    for (int j = 0; j < 4; ++j)
      bfv[j] = *(const bf16x8*)&Bs[(wc + j * 16 + lr) * 32 + q * 8];
#pragma unroll
    for (int i = 0; i < 4; ++i)
#pragma unroll
      for (int j = 0; j < 4; ++j)
        acc[i][j] = __builtin_amdgcn_mfma_f32_16x16x32_bf16(af[i], bfv[j],
                                                            acc[i][j], 0, 0, 0);
  }
}

// ---------------------------------------------------------------------------
// Kernel 1: QKV projection — r6 version VERBATIM (measured best).
// 128x288 tile, 512 blocks = 2 blocks/CU, dbuf-2, coarse 36-MFMA phases.
// qkv is schedule-insensitive (+-10%) across 6 structural variants; frozen.
// ---------------------------------------------------------------------------
#define STGP(s, p)                                                            \
  async_copy16(pa + (p) * 32,             &As[s][t * 8]);                     \
  async_copy16(pa + 64 * DIM + (p) * 32,  &As[s][2048 + t * 8]);              \
  async_copy16(pb + (p) * 32,             &Bs[s][t * 8]);                     \
  async_copy16(pb + 64 * DIM + (p) * 32,  &Bs[s][2048 + t * 8]);              \
  async_copy16(pb + 128 * DIM + (p) * 32, &Bs[s][4096 + t * 8]);              \
  async_copy16(pb + 192 * DIM + (p) * 32, &Bs[s][6144 + t * 8]);              \
  async_copy4 (pb3 + (p) * 32,            &Bs[s][8192 + t * 2]);              \
  async_copy4 (pb3 + 16 * DIM + (p) * 32, &Bs[s][8704 + t * 2])

#define PHASE(CUR, STG_, VW_) {                                               \
  bf16x8 af[4], bfv[9];                                                       \
  _Pragma("unroll") for (int mf_ = 0; mf_ < 4; ++mf_)                         \
    af[mf_] = *(const bf16x8*)&As[CUR][mf_ * 512 + arow];                     \
  _Pragma("unroll") for (int nf_ = 0; nf_ < 9; ++nf_)                         \
    bfv[nf_] = *(const bf16x8*)&Bs[CUR][nf_ * 512 + brow];                    \
  STG_; BARRIER; LGKM0;                                                       \
  __builtin_amdgcn_s_setprio(1);                                              \
  _Pragma("unroll") for (int mf_ = 0; mf_ < 4; ++mf_)                         \
  _Pragma("unroll") for (int nf_ = 0; nf_ < 9; ++nf_)                         \
    acc[mf_][nf_] = __builtin_amdgcn_mfma_f32_16x16x32_bf16(                  \
        af[mf_], bfv[nf_], acc[mf_][nf_], 0, 0, 0);                           \
  __builtin_amdgcn_s_setprio(0); VW_; BARRIER; }

__global__ void __launch_bounds__(256, 2)
gemm_qkv(const bf16* __restrict__ X, const bf16* __restrict__ W,
         const float* __restrict__ bias,
         bf16* __restrict__ qb, bf16* __restrict__ kb, bf16* __restrict__ vb) {
  __shared__ short As[2][128 * 32];   // 2 x 8 KB
  __shared__ short Bs[2][288 * 32];   // 2 x 18 KB   (total 52 KB, 2 blk/CU)
  const int t = threadIdx.x;
  const int w = t >> 6, l = t & 63, lr = l & 15, q = l >> 4;
  const int wm = w >> 1, wn = w & 1;          // 2M x 2N wave grid

  // XCD-aware bijective swizzle: 512 blocks, 64/XCD
  const int orig = blockIdx.x;
  const int swz = (orig & 7) * 64 + (orig >> 3);
  const int tm = swz >> 3, tn = swz & 7;
  const int row0 = tm * 128, col0 = tn * 288;

  const int sr = t >> 2;
  const int scol = (((t & 3) << 3) ^ (((sr >> 1) & 3) << 3));
  const bf16* pa  = X + (size_t)(row0 + sr) * DIM + scol;
  const bf16* pb  = W + (size_t)(col0 + sr) * DIM + scol;
  const int r3 = t >> 4;
  const int c3 = ((t & 15) << 1) ^ (((r3 >> 1) & 3) << 3);
  const bf16* pb3 = W + (size_t)(col0 + 256 + r3) * DIM + c3;

  const int acol = ((q << 3) ^ (((lr >> 1) & 3) << 3));
  const int arow = (wm * 64 + lr) * 32 + acol;    // + mf*512
  const int brow = (wn * 144 + lr) * 32 + acol;   // + nf*512

  float4v acc[4][9] = {};

  STGP(0, 0);
  VW0; BARRIER;

#pragma unroll 1
  for (int k = 0; k < 22; k += 2) {
    PHASE(0, STGP(1, k + 1), VW0)
    PHASE(1, STGP(0, k + 2), VW0)
  }
  PHASE(0, STGP(1, 23), VW0)   // k=22
  PHASE(1, NOSTG,       NOVW)  // k=23

#pragma unroll
  for (int nf = 0; nf < 9; ++nf) {
    const int gn = col0 + wn * 144 + nf * 16 + lr;   // 0..2303
    const int which = gn / DIM;                      // uniform per frag
    const int cc = gn - which * DIM;
    const int hh = cc >> 6, dd = cc & 63;
    const float bv = bias[gn];
#pragma unroll
    for (int mf = 0; mf < 4; ++mf) {
      const int gm0 = row0 + wm * 64 + mf * 16 + (q << 2);  // token base (x4)
      const int b = gm0 >> 11, n0 = gm0 & 2047;
      if (which == 2) {
        short4v pv;
#pragma unroll
        for (int r = 0; r < 4; ++r) pv[r] = f2bf(acc[mf][nf][r] + bv);
        *(short4v*)&vb[((size_t)(b * NH + hh) * HD + dd) * SEQ + n0] = pv;
      } else {
        bf16* dst = (which == 0) ? qb : kb;
        const float sc = (which == 0) ? SCALE_QL2E : 1.0f;
#pragma unroll
        for (int r = 0; r < 4; ++r)
          dst[((size_t)(b * NH + hh) * SEQ + n0 + r) * HD + dd] =
              __float2bfloat16((acc[mf][nf][r] + bv) * sc);
      }
    }
  }
}

// ---------------------------------------------------------------------------
// Kernel 2: flash attention — r10: r9 ring-2 DMA structure + VALU-diet
// softmax path.
//
// r9 counters: VALUBusy 43-45% is the top pipe and sits on the serial
// S-MFMA -> softmax -> PV-MFMA chain.  Census: 32 software-RNE
// __float2bfloat16 (~6 ops each) + 32 per-kt zero-movs for s[][].  Diet:
// (a) v_cvt_pk_bf16_f32 inline asm — 16 pack instrs/kt replace the 32
//     scalar conversions, same RNE rounding (bit-identical output);
// (b) persistent zero4 as the C-input of the first S accumulation — the
//     per-kt s zero-init disappears (MFMA writes a fresh dst).
// Everything else identical to r9 (ring-2 32 KB, one barrier/kt, drain
// after compute, source-side swizzle, l-sum via MFMA ones).
// ---------------------------------------------------------------------------
#define STG_KV(bb, k1)                                                        \
  async_copy16(Kb + (size_t)((k1) + drow) * HD + skey,       &KV[bb][t * 8]); \
  async_copy16(Kb + (size_t)((k1) + 32 + drow) * HD + skey,  &KV[bb][2048 + t * 8]); \
  async_copy16(Vb + (size_t)drow * SEQ + (k1) + skey,        &KV[bb][4096 + t * 8]); \
  async_copy16(Vb + (size_t)(32 + drow) * SEQ + (k1) + skey, &KV[bb][6144 + t * 8])

__global__ void __launch_bounds__(256, 3)
flash_attn(const bf16* __restrict__ Qp, const bf16* __restrict__ Kp,
           const bf16* __restrict__ Vtp, bf16* __restrict__ Op) {
  const int bh = blockIdx.y, qt = blockIdx.x;
  const int t = threadIdx.x, w = t >> 6, l = t & 63, lr = l & 15, q = l >> 4;
  __shared__ short KV[2][8192];   // ring-2: {K[64][64] | V^T[64][64]}, 32 KB

  const bf16* Qb = Qp  + (size_t)(bh * SEQ + qt * 128) * HD;
  const bf16* Kb = Kp  + (size_t)bh * SEQ * HD;
  const bf16* Vb = Vtp + (size_t)bh * HD * SEQ;   // [d][n]

  // DMA coords: thread t -> dest row t>>3, 16B-slot t&7 (linear);
  // source col carries the inverse swizzle (involution)
  const int drow = t >> 3;
  const int skey = (((t & 7) ^ drow) & 7) * 8;

  // Q fragments straight from global (once per kernel)
  bf16x8 qf[2][2];
#pragma unroll
  for (int it = 0; it < 2; ++it)
#pragma unroll
    for (int kq = 0; kq < 2; ++kq)
      qf[it][kq] = *(const bf16x8*)(Qb + (size_t)(w * 32 + it * 16 + lr) * HD +
                                    kq * 32 + q * 8);

  // read-side swizzle key: all frag rows have (row&7) == (lr&7)
  const int key8 = (lr & 7) << 3;

  frag8 ones;            // all-ones bf16 B-fragment for the l row-sum MFMA
#pragma unroll
  for (int r = 0; r < 8; ++r) ones.s[r] = (short)0x3F80;

  const float4v zero4 = {};   // persistent zero C-input (kills per-kt movs)

  float4v o[2][4] = {};
  float4v lacc[2] = {};  // l, col-replicated in C/D layout

  // prologue: tile 0 -> buf 0, drain, barrier
  STG_KV(0, 0);
  VW0; BARRIER;

  for (int kt = 0; kt < 32; ++kt) {
    if (kt < 31) { STG_KV((kt + 1) & 1, (kt + 1) * 64); }
    const short* Bf = KV[kt & 1];

    // S^T = K * Q^T : tiles [kk 4][qr 2]; first MFMA uses zero4 as C
    float4v s[4][2];
    __builtin_amdgcn_s_setprio(1);
#pragma unroll
    for (int jn = 0; jn < 4; ++jn) {
      bf16x8 kf[2];
#pragma unroll
      for (int kq = 0; kq < 2; ++kq)
        kf[kq] = *(const bf16x8*)&Bf[(jn * 16 + lr) * 64 +
                                     (((kq * 32) + (q << 3)) ^ key8)];
#pragma unroll
      for (int it = 0; it < 2; ++it) {
        float4v s0 = __builtin_amdgcn_mfma_f32_16x16x32_bf16(kf[0], qf[it][0],
                                                             zero4, 0, 0, 0);
        s[jn][it]  = __builtin_amdgcn_mfma_f32_16x16x32_bf16(kf[1], qf[it][1],
                                                             s0, 0, 0, 0);
      }
    }
    __builtin_amdgcn_s_setprio(0);

    // p = exp2(s); pack via v_cvt_pk_bf16_f32 (word j = shorts {2j, 2j+1});
    // slot mapping unchanged: (q,j) <-> kk = 32c + 16*(j>>2) + 4q + (j&3)
    frag8 pf[2][2];
#pragma unroll
    for (int it = 0; it < 2; ++it)
#pragma unroll
      for (int c4 = 0; c4 < 2; ++c4) {
        float e[8];
#pragma unroll
        for (int r = 0; r < 4; ++r) {
          e[r]     = __builtin_amdgcn_exp2f(s[2 * c4][it][r]);
          e[4 + r] = __builtin_amdgcn_exp2f(s[2 * c4 + 1][it][r]);
        }
        pf[c4][it].u[0] = cvtpk_bf16(e[0], e[1]);
        pf[c4][it].u[1] = cvtpk_bf16(e[2], e[3]);
        pf[c4][it].u[2] = cvtpk_bf16(e[4], e[5]);
        pf[c4][it].u[3] = cvtpk_bf16(e[6], e[7]);
      }

    // O += P * V ; l += P * 1  (B mirrors the paired-k slot mapping)
    __builtin_amdgcn_s_setprio(1);
#pragma unroll
    for (int c4 = 0; c4 < 2; ++c4) {
#pragma unroll
      for (int dj = 0; dj < 4; ++dj) {
        frag8 vf;
        vf.h[0] = *(const short4v*)&Bf[4096 + (dj * 16 + lr) * 64 +
                                       ((c4 * 32 + (q << 2)) ^ key8)];
        vf.h[1] = *(const short4v*)&Bf[4096 + (dj * 16 + lr) * 64 +
                                       ((c4 * 32 + 16 + (q << 2)) ^ key8)];
#pragma unroll
        for (int it = 0; it < 2; ++it)
          o[it][dj] = __builtin_amdgcn_mfma_f32_16x16x32_bf16(pf[c4][it].b, vf.b,
                                                              o[it][dj], 0, 0, 0);
      }
#pragma unroll
      for (int it = 0; it < 2; ++it)
        lacc[it] = __builtin_amdgcn_mfma_f32_16x16x32_bf16(pf[c4][it].b, ones.b,
                                                           lacc[it], 0, 0, 0);
    }
    __builtin_amdgcn_s_setprio(0);

    if (kt < 31) { VW0; BARRIER; }   // drain own DMA AFTER compute; next tile
  }

  // epilogue: linv directly per lane (lacc col-replicated), no shuffles
  const int b = bh / NH, h = bh - b * NH;
#pragma unroll
  for (int it = 0; it < 2; ++it)
#pragma unroll
    for (int r = 0; r < 4; ++r) {
      const float linv = 1.0f / lacc[it][r];
      const int grow = b * SEQ + qt * 128 + w * 32 + it * 16 + (q << 2) + r;
      bf16* orow = Op + (size_t)grow * DIM + h * HD;
#pragma unroll
      for (int dj = 0; dj < 4; ++dj)
        orow[dj * 16 + lr] = __float2bfloat16(o[it][dj][r] * linv);
    }
}

// ---------------------------------------------------------------------------
// Kernel 3: output projection.  AO[8192,768](bf16) @ w_proj^T(bf16) + b -> f32
// (unchanged this round)
// ---------------------------------------------------------------------------
__global__ void __launch_bounds__(256)
gemm_proj(const bf16* __restrict__ A, const bf16* __restrict__ W,
          const float* __restrict__ bias, float* __restrict__ out) {
  __shared__ short As[128 * 32];
  __shared__ short Bs[128 * 32];
  const int t = threadIdx.x;
  const int w = t >> 6, l = t & 63, lr = l & 15, q = l >> 4;
  const int wr = ((w >> 1) << 6), wc = ((w & 1) << 6);
  const int row0 = blockIdx.y * 128, col0 = blockIdx.x * 128;

  float4v acc[4][4] = {};
  gemm_mainloop(A + row0 * DIM, W + col0 * DIM, As, Bs, acc);

#pragma unroll
  for (int j = 0; j < 4; ++j) {
    const int gn = col0 + wc + j * 16 + lr;
    const float bv = bias[gn];
#pragma unroll
    for (int i = 0; i < 4; ++i) {
#pragma unroll
      for (int r = 0; r < 4; ++r) {
        const int gm = row0 + wr + i * 16 + (q << 2) + r;
        out[(size_t)gm * DIM + gn] = acc[i][j][r] + bv;
      }
    }
  }
}

// ---------------------------------------------------------------------------
extern "C" void kernel_launch(void* const* d_in, const int* in_sizes, int n_in,
                              void* d_out, int out_size, void* d_ws, size_t ws_size,
                              hipStream_t stream) {
  const float* x      = (const float*)d_in[0];
  const float* w_qkv  = (const float*)d_in[1];
  const float* b_qkv  = (const float*)d_in[2];
  const float* w_proj = (const float*)d_in[3];
  const float* b_proj = (const float*)d_in[4];
  float* out = (float*)d_out;

  const size_t perbuf = (size_t)BATCH * NH * SEQ * HD;  // 6291456 elems
  bf16* qb  = (bf16*)d_ws;
  bf16* kb  = qb + perbuf;
  bf16* vb  = kb + perbuf;          // [B,H,64,N] transposed
  bf16* ao  = vb + perbuf;
  bf16* xb  = ao + perbuf;          // NX
  bf16* wqb = xb + (size_t)NX;      // NWQ
  bf16* wpb = wqb + (size_t)NWQ;    // NWP

  const int cvt_blocks = (NX + NWQ + NWP) / 8 / 256;   // 4224
  cvt3<<<cvt_blocks, 256, 0, stream>>>(x, xb, NX, w_qkv, wqb, NWQ, w_proj, wpb, NWP);
  gemm_qkv <<<dim3(512), 256, 0, stream>>>(xb, wqb, b_qkv, qb, kb, vb);
  flash_attn<<<dim3(SEQ / 128, BATCH * NH), 256, 0, stream>>>(qb, kb, vb, ao);
  gemm_proj <<<dim3(DIM / 128, TOK / 128),  256, 0, stream>>>(ao, wpb, b_proj, out);
}

// Round 11
// 203.213 us; speedup vs baseline: 1.0122x; 1.0122x over previous
//
#include <hip/hip_runtime.h>
#include <hip/hip_bf16.h>

using bf16 = __hip_bfloat16;
typedef __bf16 bf16x8 __attribute__((ext_vector_type(8)));
typedef short short4v __attribute__((ext_vector_type(4)));
typedef short short8v __attribute__((ext_vector_type(8)));
typedef float float4v __attribute__((ext_vector_type(4)));

#define DIM   768
#define NH    12
#define HD    64
#define SEQ   2048
#define BATCH 4
#define TOK   (BATCH * SEQ)   // 8192
// softmax scale * log2(e) folded into q at QKV epilogue (flash uses exp2)
#define SCALE_QL2E 0.18033688011112042f

#define NX  (TOK * DIM)        // 6291456
#define NWQ (3 * DIM * DIM)    // 1769472
#define NWP (DIM * DIM)        //  589824

__device__ __forceinline__ short f2bf(float f) {
  union { bf16 h; short s; } u;
  u.h = __float2bfloat16(f);
  return u.s;
}

union frag8 { short4v h[2]; short8v s; bf16x8 b; unsigned u[4]; };

// global(16B) -> LDS async DMA; LDS dest must be wave-uniform base + lane*16B
__device__ __forceinline__ void async_copy16(const bf16* g, short* l) {
  __builtin_amdgcn_global_load_lds(
      (const __attribute__((address_space(1))) unsigned int*)g,
      (__attribute__((address_space(3))) unsigned int*)l, 16, 0, 0);
}
// 4B variant (partial-row staging; dest = base + lane*4B)
__device__ __forceinline__ void async_copy4(const bf16* g, short* l) {
  __builtin_amdgcn_global_load_lds(
      (const __attribute__((address_space(1))) unsigned int*)g,
      (__attribute__((address_space(3))) unsigned int*)l, 4, 0, 0);
}

#define BARRIER __builtin_amdgcn_s_barrier()
#define LGKM0 asm volatile("s_waitcnt lgkmcnt(0)" ::: "memory")
#define VW0 asm volatile("s_waitcnt vmcnt(0)" ::: "memory")
#define NOSTG (void)0
#define NOVW  (void)0

// ---------------------------------------------------------------------------
// Kernel 0: f32 -> bf16 convert for x, w_qkv, w_proj (one fused launch)
// ---------------------------------------------------------------------------
__global__ void __launch_bounds__(256)
cvt3(const float* __restrict__ a, bf16* __restrict__ oa, long na,
     const float* __restrict__ b, bf16* __restrict__ ob, long nb,
     const float* __restrict__ c, bf16* __restrict__ oc, long nc) {
  const long i = ((long)blockIdx.x * 256 + threadIdx.x) * 8;
  const float* src; bf16* dst; long off;
  if (i < na)                { src = a; dst = oa; off = i; }
  else if (i < na + nb)      { src = b; dst = ob; off = i - na; }
  else if (i < na + nb + nc) { src = c; dst = oc; off = i - na - nb; }
  else return;
  const float4v x0 = *(const float4v*)(src + off);
  const float4v x1 = *(const float4v*)(src + off + 4);
  short8v r;
  r[0] = f2bf(x0[0]); r[1] = f2bf(x0[1]); r[2] = f2bf(x0[2]); r[3] = f2bf(x0[3]);
  r[4] = f2bf(x1[0]); r[5] = f2bf(x1[1]); r[6] = f2bf(x1[2]); r[7] = f2bf(x1[3]);
  *(short8v*)(dst + off) = r;
}

// ---------------------------------------------------------------------------
// Shared 128x128 bf16 GEMM main loop (m97 structure) — still used by gemm_proj
// ---------------------------------------------------------------------------
__device__ __forceinline__ void gemm_mainloop(const bf16* __restrict__ A,
                                              const bf16* __restrict__ B,
                                              short* As, short* Bs,
                                              float4v acc[4][4]) {
  const int t = threadIdx.x;
  const int w = t >> 6, l = t & 63, lr = l & 15, q = l >> 4;
  const int wr = ((w >> 1) << 6), wc = ((w & 1) << 6);

  const bf16* Ag = A + (t >> 2) * DIM + (t & 3) * 8;
  const bf16* Bg = B + (t >> 2) * DIM + (t & 3) * 8;

  for (int k0 = 0; k0 < DIM; k0 += 32) {
    __syncthreads();                       // previous tile's consumers done
    async_copy16(Ag,            &As[t * 8]);
    async_copy16(Ag + 64 * DIM, &As[2048 + t * 8]);
    async_copy16(Bg,            &Bs[t * 8]);
    async_copy16(Bg + 64 * DIM, &Bs[2048 + t * 8]);
    Ag += 32; Bg += 32;
    __syncthreads();                       // vmcnt(0) drain before barrier

    bf16x8 af[4], bfv[4];
#pragma unroll
    for (int i = 0; i < 4; ++i)
      af[i] = *(const bf16x8*)&As[(wr + i * 16 + lr) * 32 + q * 8];
#pragma unroll
    for (int j = 0; j < 4; ++j)
      bfv[j] = *(const bf16x8*)&Bs[(wc + j * 16 + lr) * 32 + q * 8];
#pragma unroll
    for (int i = 0; i < 4; ++i)
#pragma unroll
      for (int j = 0; j < 4; ++j)
        acc[i][j] = __builtin_amdgcn_mfma_f32_16x16x32_bf16(af[i], bfv[j],
                                                            acc[i][j], 0, 0, 0);
  }
}

// ---------------------------------------------------------------------------
// Kernel 1: QKV projection — r6 version VERBATIM (measured best).
// 128x288 tile, 512 blocks = 2 blocks/CU, dbuf-2, coarse 36-MFMA phases.
// qkv is schedule-insensitive (+-10%) across 6 structural variants; frozen.
// ---------------------------------------------------------------------------
#define STGP(s, p)                                                            \
  async_copy16(pa + (p) * 32,             &As[s][t * 8]);                     \
  async_copy16(pa + 64 * DIM + (p) * 32,  &As[s][2048 + t * 8]);              \
  async_copy16(pb + (p) * 32,             &Bs[s][t * 8]);                     \
  async_copy16(pb + 64 * DIM + (p) * 32,  &Bs[s][2048 + t * 8]);              \
  async_copy16(pb + 128 * DIM + (p) * 32, &Bs[s][4096 + t * 8]);              \
  async_copy16(pb + 192 * DIM + (p) * 32, &Bs[s][6144 + t * 8]);              \
  async_copy4 (pb3 + (p) * 32,            &Bs[s][8192 + t * 2]);              \
  async_copy4 (pb3 + 16 * DIM + (p) * 32, &Bs[s][8704 + t * 2])

#define PHASE(CUR, STG_, VW_) {                                               \
  bf16x8 af[4], bfv[9];                                                       \
  _Pragma("unroll") for (int mf_ = 0; mf_ < 4; ++mf_)                         \
    af[mf_] = *(const bf16x8*)&As[CUR][mf_ * 512 + arow];                     \
  _Pragma("unroll") for (int nf_ = 0; nf_ < 9; ++nf_)                         \
    bfv[nf_] = *(const bf16x8*)&Bs[CUR][nf_ * 512 + brow];                    \
  STG_; BARRIER; LGKM0;                                                       \
  __builtin_amdgcn_s_setprio(1);                                              \
  _Pragma("unroll") for (int mf_ = 0; mf_ < 4; ++mf_)                         \
  _Pragma("unroll") for (int nf_ = 0; nf_ < 9; ++nf_)                         \
    acc[mf_][nf_] = __builtin_amdgcn_mfma_f32_16x16x32_bf16(                  \
        af[mf_], bfv[nf_], acc[mf_][nf_], 0, 0, 0);                           \
  __builtin_amdgcn_s_setprio(0); VW_; BARRIER; }

__global__ void __launch_bounds__(256, 2)
gemm_qkv(const bf16* __restrict__ X, const bf16* __restrict__ W,
         const float* __restrict__ bias,
         bf16* __restrict__ qb, bf16* __restrict__ kb, bf16* __restrict__ vb) {
  __shared__ short As[2][128 * 32];   // 2 x 8 KB
  __shared__ short Bs[2][288 * 32];   // 2 x 18 KB   (total 52 KB, 2 blk/CU)
  const int t = threadIdx.x;
  const int w = t >> 6, l = t & 63, lr = l & 15, q = l >> 4;
  const int wm = w >> 1, wn = w & 1;          // 2M x 2N wave grid

  // XCD-aware bijective swizzle: 512 blocks, 64/XCD
  const int orig = blockIdx.x;
  const int swz = (orig & 7) * 64 + (orig >> 3);
  const int tm = swz >> 3, tn = swz & 7;
  const int row0 = tm * 128, col0 = tn * 288;

  const int sr = t >> 2;
  const int scol = (((t & 3) << 3) ^ (((sr >> 1) & 3) << 3));
  const bf16* pa  = X + (size_t)(row0 + sr) * DIM + scol;
  const bf16* pb  = W + (size_t)(col0 + sr) * DIM + scol;
  const int r3 = t >> 4;
  const int c3 = ((t & 15) << 1) ^ (((r3 >> 1) & 3) << 3);
  const bf16* pb3 = W + (size_t)(col0 + 256 + r3) * DIM + c3;

  const int acol = ((q << 3) ^ (((lr >> 1) & 3) << 3));
  const int arow = (wm * 64 + lr) * 32 + acol;    // + mf*512
  const int brow = (wn * 144 + lr) * 32 + acol;   // + nf*512

  float4v acc[4][9] = {};

  STGP(0, 0);
  VW0; BARRIER;

#pragma unroll 1
  for (int k = 0; k < 22; k += 2) {
    PHASE(0, STGP(1, k + 1), VW0)
    PHASE(1, STGP(0, k + 2), VW0)
  }
  PHASE(0, STGP(1, 23), VW0)   // k=22
  PHASE(1, NOSTG,       NOVW)  // k=23

#pragma unroll
  for (int nf = 0; nf < 9; ++nf) {
    const int gn = col0 + wn * 144 + nf * 16 + lr;   // 0..2303
    const int which = gn / DIM;                      // uniform per frag
    const int cc = gn - which * DIM;
    const int hh = cc >> 6, dd = cc & 63;
    const float bv = bias[gn];
#pragma unroll
    for (int mf = 0; mf < 4; ++mf) {
      const int gm0 = row0 + wm * 64 + mf * 16 + (q << 2);  // token base (x4)
      const int b = gm0 >> 11, n0 = gm0 & 2047;
      if (which == 2) {
        short4v pv;
#pragma unroll
        for (int r = 0; r < 4; ++r) pv[r] = f2bf(acc[mf][nf][r] + bv);
        *(short4v*)&vb[((size_t)(b * NH + hh) * HD + dd) * SEQ + n0] = pv;
      } else {
        bf16* dst = (which == 0) ? qb : kb;
        const float sc = (which == 0) ? SCALE_QL2E : 1.0f;
#pragma unroll
        for (int r = 0; r < 4; ++r)
          dst[((size_t)(b * NH + hh) * SEQ + n0 + r) * HD + dd] =
              __float2bfloat16((acc[mf][nf][r] + bv) * sc);
      }
    }
  }
}

// ---------------------------------------------------------------------------
// Kernel 2: flash attention — r11: r9 ring-2 DMA structure upgraded to a
// T15 software pipeline on a RING-3 (48 KB, still 3 blocks/CU).
//
// r10 post-mortem: cvt_pk asm was neutral (compiler already efficient) —
// softmax code reverted to r9 verbatim.  r9's remaining loss is the serial
// in-wave chain S-MFMA -> softmax(VALU) -> PV-MFMA (both pipes <45%, ~22%
// idle).  T15: per iter kt issue {S(kt) MFMA | PV(kt-1) MFMA | STG(kt+1) |
// softmax(kt) VALU} — PV(kt-1) consumes LAST iter's pf, independent of
// S(kt), so the softmax VALU overlaps the PV MFMA drain (dual-pipe).
//
// Ring-3 race analysis (ONE barrier/iter): STG(kt+1)->buf[(kt+1)%3] issues
// after B_kt; that buffer's last reader PV(kt-2) ran before B_kt (iter
// kt-1's span) -> no WAR.  VW0 before each barrier drains each wave's own
// DMA -> K[kt+1]/V[kt] complete before read -> no RAW.  S reads bK, PV
// reads bP, STG writes bN — all distinct mod-3 -> no same-span conflict.
//
// pf double-buffer is STATIC (named pfA/pfB, pair-unrolled loop) per
// rule #20 (runtime-indexed reg arrays go to scratch).
// ---------------------------------------------------------------------------
#define STG_KV(bb, k1)                                                        \
  async_copy16(Kb + (size_t)((k1) + drow) * HD + skey,       &KV[bb][t * 8]); \
  async_copy16(Kb + (size_t)((k1) + 32 + drow) * HD + skey,  &KV[bb][2048 + t * 8]); \
  async_copy16(Vb + (size_t)drow * SEQ + (k1) + skey,        &KV[bb][4096 + t * 8]); \
  async_copy16(Vb + (size_t)(32 + drow) * SEQ + (k1) + skey, &KV[bb][6144 + t * 8])

#define S_STEP(BK_) {                                                         \
  const short* Bf_ = KV[BK_];                                                 \
  __builtin_amdgcn_s_setprio(1);                                              \
  _Pragma("unroll") for (int jn = 0; jn < 4; ++jn) {                          \
    bf16x8 kf[2];                                                             \
    _Pragma("unroll") for (int kq = 0; kq < 2; ++kq)                          \
      kf[kq] = *(const bf16x8*)&Bf_[(jn * 16 + lr) * 64 +                     \
                                    (((kq * 32) + (q << 3)) ^ key8)];         \
    _Pragma("unroll") for (int it = 0; it < 2; ++it)                          \
    _Pragma("unroll") for (int kq = 0; kq < 2; ++kq)                          \
      s[jn][it] = __builtin_amdgcn_mfma_f32_16x16x32_bf16(kf[kq],             \
                      qf[it][kq], s[jn][it], 0, 0, 0);                        \
  }                                                                           \
  __builtin_amdgcn_s_setprio(0); }

#define PV_STEP(PF_, BP_) {                                                   \
  const short* Bv_ = KV[BP_] + 4096;                                          \
  __builtin_amdgcn_s_setprio(1);                                              \
  _Pragma("unroll") for (int c4 = 0; c4 < 2; ++c4) {                          \
    _Pragma("unroll") for (int dj = 0; dj < 4; ++dj) {                        \
      frag8 vf;                                                               \
      vf.h[0] = *(const short4v*)&Bv_[(dj * 16 + lr) * 64 +                   \
                                      ((c4 * 32 + (q << 2)) ^ key8)];         \
      vf.h[1] = *(const short4v*)&Bv_[(dj * 16 + lr) * 64 +                   \
                                      ((c4 * 32 + 16 + (q << 2)) ^ key8)];    \
      _Pragma("unroll") for (int it = 0; it < 2; ++it)                        \
        o[it][dj] = __builtin_amdgcn_mfma_f32_16x16x32_bf16(PF_[c4][it].b,    \
                        vf.b, o[it][dj], 0, 0, 0);                            \
    }                                                                         \
    _Pragma("unroll") for (int it = 0; it < 2; ++it)                          \
      lacc[it] = __builtin_amdgcn_mfma_f32_16x16x32_bf16(PF_[c4][it].b,       \
                     ones.b, lacc[it], 0, 0, 0);                              \
  }                                                                           \
  __builtin_amdgcn_s_setprio(0); }

#define SM_STEP(PF_)                                                          \
  _Pragma("unroll") for (int it = 0; it < 2; ++it)                            \
  _Pragma("unroll") for (int c4 = 0; c4 < 2; ++c4)                            \
  _Pragma("unroll") for (int r = 0; r < 4; ++r) {                             \
    PF_[c4][it].s[r]     = f2bf(__builtin_amdgcn_exp2f(s[2 * c4][it][r]));    \
    PF_[c4][it].s[4 + r] = f2bf(__builtin_amdgcn_exp2f(s[2 * c4 + 1][it][r]));\
  }

#define FA_BODY(BK_, BP_, BN_, PFP_, PFC_, TILE1_) {                          \
  float4v s[4][2] = {};                                                       \
  S_STEP(BK_);                                                                \
  PV_STEP(PFP_, BP_);                                                         \
  STG_KV(BN_, (TILE1_) * 64);                                                 \
  SM_STEP(PFC_);                                                              \
  VW0; BARRIER; }

__global__ void __launch_bounds__(256, 3)
flash_attn(const bf16* __restrict__ Qp, const bf16* __restrict__ Kp,
           const bf16* __restrict__ Vtp, bf16* __restrict__ Op) {
  const int bh = blockIdx.y, qt = blockIdx.x;
  const int t = threadIdx.x, w = t >> 6, l = t & 63, lr = l & 15, q = l >> 4;
  __shared__ short KV[3][8192];   // ring-3: {K[64][64] | V^T[64][64]}, 48 KB

  const bf16* Qb = Qp  + (size_t)(bh * SEQ + qt * 128) * HD;
  const bf16* Kb = Kp  + (size_t)bh * SEQ * HD;
  const bf16* Vb = Vtp + (size_t)bh * HD * SEQ;   // [d][n]

  // DMA coords: thread t -> dest row t>>3, 16B-slot t&7 (linear);
  // source col carries the inverse swizzle (involution)
  const int drow = t >> 3;
  const int skey = (((t & 7) ^ drow) & 7) * 8;

  // Q fragments straight from global (once per kernel)
  bf16x8 qf[2][2];
#pragma unroll
  for (int it = 0; it < 2; ++it)
#pragma unroll
    for (int kq = 0; kq < 2; ++kq)
      qf[it][kq] = *(const bf16x8*)(Qb + (size_t)(w * 32 + it * 16 + lr) * HD +
                                    kq * 32 + q * 8);

  // read-side swizzle key: all frag rows have (row&7) == (lr&7)
  const int key8 = (lr & 7) << 3;

  frag8 ones;            // all-ones bf16 B-fragment for the l row-sum MFMA
#pragma unroll
  for (int r = 0; r < 8; ++r) ones.s[r] = (short)0x3F80;

  float4v o[2][4] = {};
  float4v lacc[2] = {};  // l, col-replicated in C/D layout
  frag8 pfA[2][2], pfB[2][2];

  // prologue: tile 0 -> buf 0, drain, barrier
  STG_KV(0, 0);
  VW0; BARRIER;

  // iter 0: S(0), no PV, stage tile 1, softmax(0)->pfA
  {
    float4v s[4][2] = {};
    S_STEP(0);
    STG_KV(1, 64);
    SM_STEP(pfA);
    VW0; BARRIER;
  }

  // steady pairs kt = 1..30 (pf parity: even softmax->pfA, odd->pfB)
  int bK = 1;                        // buf of tile kt at pair top (kt%3)
#pragma unroll 1
  for (int kt = 1; kt < 31; kt += 2) {
    const int bP = (bK == 0) ? 2 : bK - 1;
    const int bN = (bK == 2) ? 0 : bK + 1;
    FA_BODY(bK, bP, bN, pfA, pfB, kt + 1)   // kt (odd):  PV(kt-1)=pfA -> pfB
    FA_BODY(bN, bK, bP, pfB, pfA, kt + 2)   // kt+1(even):PV(kt)=pfB  -> pfA
    bK = bP;                                // advance +2 mod 3
  }

  // kt = 31 (buf 1): S(31), PV(30)=pfA (buf 0), softmax(31)->pfB,
  // then drain the pipeline: PV(31)=pfB (V[31] in buf 1)
  {
    float4v s[4][2] = {};
    S_STEP(1);
    PV_STEP(pfA, 0);
    SM_STEP(pfB);
    PV_STEP(pfB, 1);
  }

  // epilogue: linv directly per lane (lacc col-replicated), no shuffles
  const int b = bh / NH, h = bh - b * NH;
#pragma unroll
  for (int it = 0; it < 2; ++it)
#pragma unroll
    for (int r = 0; r < 4; ++r) {
      const float linv = 1.0f / lacc[it][r];
      const int grow = b * SEQ + qt * 128 + w * 32 + it * 16 + (q << 2) + r;
      bf16* orow = Op + (size_t)grow * DIM + h * HD;
#pragma unroll
      for (int dj = 0; dj < 4; ++dj)
        orow[dj * 16 + lr] = __float2bfloat16(o[it][dj][r] * linv);
    }
}

// ---------------------------------------------------------------------------
// Kernel 3: output projection.  AO[8192,768](bf16) @ w_proj^T(bf16) + b -> f32
// (unchanged this round)
// ---------------------------------------------------------------------------
__global__ void __launch_bounds__(256)
gemm_proj(const bf16* __restrict__ A, const bf16* __restrict__ W,
          const float* __restrict__ bias, float* __restrict__ out) {
  __shared__ short As[128 * 32];
  __shared__ short Bs[128 * 32];
  const int t = threadIdx.x;
  const int w = t >> 6, l = t & 63, lr = l & 15, q = l >> 4;
  const int wr = ((w >> 1) << 6), wc = ((w & 1) << 6);
  const int row0 = blockIdx.y * 128, col0 = blockIdx.x * 128;

  float4v acc[4][4] = {};
  gemm_mainloop(A + row0 * DIM, W + col0 * DIM, As, Bs, acc);

#pragma unroll
  for (int j = 0; j < 4; ++j) {
    const int gn = col0 + wc + j * 16 + lr;
    const float bv = bias[gn];
#pragma unroll
    for (int i = 0; i < 4; ++i) {
#pragma unroll
      for (int r = 0; r < 4; ++r) {
        const int gm = row0 + wr + i * 16 + (q << 2) + r;
        out[(size_t)gm * DIM + gn] = acc[i][j][r] + bv;
      }
    }
  }
}

// ---------------------------------------------------------------------------
extern "C" void kernel_launch(void* const* d_in, const int* in_sizes, int n_in,
                              void* d_out, int out_size, void* d_ws, size_t ws_size,
                              hipStream_t stream) {
  const float* x      = (const float*)d_in[0];
  const float* w_qkv  = (const float*)d_in[1];
  const float* b_qkv  = (const float*)d_in[2];
  const float* w_proj = (const float*)d_in[3];
  const float* b_proj = (const float*)d_in[4];
  float* out = (float*)d_out;

  const size_t perbuf = (size_t)BATCH * NH * SEQ * HD;  // 6291456 elems
  bf16* qb  = (bf16*)d_ws;
  bf16* kb  = qb + perbuf;
  bf16* vb  = kb + perbuf;          // [B,H,64,N] transposed
  bf16* ao  = vb + perbuf;
  bf16* xb  = ao + perbuf;          // NX
  bf16* wqb = xb + (size_t)NX;      // NWQ
  bf16* wpb = wqb + (size_t)NWQ;    // NWP

  const int cvt_blocks = (NX + NWQ + NWP) / 8 / 256;   // 4224
  cvt3<<<cvt_blocks, 256, 0, stream>>>(x, xb, NX, w_qkv, wqb, NWQ, w_proj, wpb, NWP);
  gemm_qkv <<<dim3(512), 256, 0, stream>>>(xb, wqb, b_qkv, qb, kb, vb);
  flash_attn<<<dim3(SEQ / 128, BATCH * NH), 256, 0, stream>>>(qb, kb, vb, ao);
  gemm_proj <<<dim3(DIM / 128, TOK / 128),  256, 0, stream>>>(ao, wpb, b_proj, out);
}

// Round 12
// 194.723 us; speedup vs baseline: 1.0563x; 1.0436x over previous
//
#include <hip/hip_runtime.h>
#include <hip/hip_bf16.h>

using bf16 = __hip_bfloat16;
typedef __bf16 bf16x8 __attribute__((ext_vector_type(8)));
typedef short short4v __attribute__((ext_vector_type(4)));
typedef short short8v __attribute__((ext_vector_type(8)));
typedef float float4v __attribute__((ext_vector_type(4)));

#define DIM   768
#define NH    12
#define HD    64
#define SEQ   2048
#define BATCH 4
#define TOK   (BATCH * SEQ)   // 8192
// softmax scale * log2(e) folded into q at QKV epilogue (flash uses exp2)
#define SCALE_QL2E 0.18033688011112042f

#define NX  (TOK * DIM)        // 6291456
#define NWQ (3 * DIM * DIM)    // 1769472
#define NWP (DIM * DIM)        //  589824

__device__ __forceinline__ short f2bf(float f) {
  union { bf16 h; short s; } u;
  u.h = __float2bfloat16(f);
  return u.s;
}

union frag8 { short4v h[2]; short8v s; bf16x8 b; unsigned u[4]; };

// global(16B) -> LDS async DMA; LDS dest must be wave-uniform base + lane*16B
__device__ __forceinline__ void async_copy16(const bf16* g, short* l) {
  __builtin_amdgcn_global_load_lds(
      (const __attribute__((address_space(1))) unsigned int*)g,
      (__attribute__((address_space(3))) unsigned int*)l, 16, 0, 0);
}
// 4B variant (partial-row staging; dest = base + lane*4B)
__device__ __forceinline__ void async_copy4(const bf16* g, short* l) {
  __builtin_amdgcn_global_load_lds(
      (const __attribute__((address_space(1))) unsigned int*)g,
      (__attribute__((address_space(3))) unsigned int*)l, 4, 0, 0);
}

#define BARRIER __builtin_amdgcn_s_barrier()
#define LGKM0 asm volatile("s_waitcnt lgkmcnt(0)" ::: "memory")
#define VW0 asm volatile("s_waitcnt vmcnt(0)" ::: "memory")
#define NOSTG (void)0
#define NOVW  (void)0

// ---------------------------------------------------------------------------
// Kernel 0: f32 -> bf16 convert for x, w_qkv, w_proj (one fused launch)
// ---------------------------------------------------------------------------
__global__ void __launch_bounds__(256)
cvt3(const float* __restrict__ a, bf16* __restrict__ oa, long na,
     const float* __restrict__ b, bf16* __restrict__ ob, long nb,
     const float* __restrict__ c, bf16* __restrict__ oc, long nc) {
  const long i = ((long)blockIdx.x * 256 + threadIdx.x) * 8;
  const float* src; bf16* dst; long off;
  if (i < na)                { src = a; dst = oa; off = i; }
  else if (i < na + nb)      { src = b; dst = ob; off = i - na; }
  else if (i < na + nb + nc) { src = c; dst = oc; off = i - na - nb; }
  else return;
  const float4v x0 = *(const float4v*)(src + off);
  const float4v x1 = *(const float4v*)(src + off + 4);
  short8v r;
  r[0] = f2bf(x0[0]); r[1] = f2bf(x0[1]); r[2] = f2bf(x0[2]); r[3] = f2bf(x0[3]);
  r[4] = f2bf(x1[0]); r[5] = f2bf(x1[1]); r[6] = f2bf(x1[2]); r[7] = f2bf(x1[3]);
  *(short8v*)(dst + off) = r;
}

// ---------------------------------------------------------------------------
// Kernel 1: QKV projection — r6 version VERBATIM (measured best).
// 128x288 tile, 512 blocks = 2 blocks/CU, dbuf-2, coarse 36-MFMA phases.
// qkv is schedule-insensitive (+-10%) across 6 structural variants; frozen.
// ---------------------------------------------------------------------------
#define STGP(s, p)                                                            \
  async_copy16(pa + (p) * 32,             &As[s][t * 8]);                     \
  async_copy16(pa + 64 * DIM + (p) * 32,  &As[s][2048 + t * 8]);              \
  async_copy16(pb + (p) * 32,             &Bs[s][t * 8]);                     \
  async_copy16(pb + 64 * DIM + (p) * 32,  &Bs[s][2048 + t * 8]);              \
  async_copy16(pb + 128 * DIM + (p) * 32, &Bs[s][4096 + t * 8]);              \
  async_copy16(pb + 192 * DIM + (p) * 32, &Bs[s][6144 + t * 8]);              \
  async_copy4 (pb3 + (p) * 32,            &Bs[s][8192 + t * 2]);              \
  async_copy4 (pb3 + 16 * DIM + (p) * 32, &Bs[s][8704 + t * 2])

#define PHASE(CUR, STG_, VW_) {                                               \
  bf16x8 af[4], bfv[9];                                                       \
  _Pragma("unroll") for (int mf_ = 0; mf_ < 4; ++mf_)                         \
    af[mf_] = *(const bf16x8*)&As[CUR][mf_ * 512 + arow];                     \
  _Pragma("unroll") for (int nf_ = 0; nf_ < 9; ++nf_)                         \
    bfv[nf_] = *(const bf16x8*)&Bs[CUR][nf_ * 512 + brow];                    \
  STG_; BARRIER; LGKM0;                                                       \
  __builtin_amdgcn_s_setprio(1);                                              \
  _Pragma("unroll") for (int mf_ = 0; mf_ < 4; ++mf_)                         \
  _Pragma("unroll") for (int nf_ = 0; nf_ < 9; ++nf_)                         \
    acc[mf_][nf_] = __builtin_amdgcn_mfma_f32_16x16x32_bf16(                  \
        af[mf_], bfv[nf_], acc[mf_][nf_], 0, 0, 0);                           \
  __builtin_amdgcn_s_setprio(0); VW_; BARRIER; }

__global__ void __launch_bounds__(256, 2)
gemm_qkv(const bf16* __restrict__ X, const bf16* __restrict__ W,
         const float* __restrict__ bias,
         bf16* __restrict__ qb, bf16* __restrict__ kb, bf16* __restrict__ vb) {
  __shared__ short As[2][128 * 32];   // 2 x 8 KB
  __shared__ short Bs[2][288 * 32];   // 2 x 18 KB   (total 52 KB, 2 blk/CU)
  const int t = threadIdx.x;
  const int w = t >> 6, l = t & 63, lr = l & 15, q = l >> 4;
  const int wm = w >> 1, wn = w & 1;          // 2M x 2N wave grid

  // XCD-aware bijective swizzle: 512 blocks, 64/XCD
  const int orig = blockIdx.x;
  const int swz = (orig & 7) * 64 + (orig >> 3);
  const int tm = swz >> 3, tn = swz & 7;
  const int row0 = tm * 128, col0 = tn * 288;

  const int sr = t >> 2;
  const int scol = (((t & 3) << 3) ^ (((sr >> 1) & 3) << 3));
  const bf16* pa  = X + (size_t)(row0 + sr) * DIM + scol;
  const bf16* pb  = W + (size_t)(col0 + sr) * DIM + scol;
  const int r3 = t >> 4;
  const int c3 = ((t & 15) << 1) ^ (((r3 >> 1) & 3) << 3);
  const bf16* pb3 = W + (size_t)(col0 + 256 + r3) * DIM + c3;

  const int acol = ((q << 3) ^ (((lr >> 1) & 3) << 3));
  const int arow = (wm * 64 + lr) * 32 + acol;    // + mf*512
  const int brow = (wn * 144 + lr) * 32 + acol;   // + nf*512

  float4v acc[4][9] = {};

  STGP(0, 0);
  VW0; BARRIER;

#pragma unroll 1
  for (int k = 0; k < 22; k += 2) {
    PHASE(0, STGP(1, k + 1), VW0)
    PHASE(1, STGP(0, k + 2), VW0)
  }
  PHASE(0, STGP(1, 23), VW0)   // k=22
  PHASE(1, NOSTG,       NOVW)  // k=23

#pragma unroll
  for (int nf = 0; nf < 9; ++nf) {
    const int gn = col0 + wn * 144 + nf * 16 + lr;   // 0..2303
    const int which = gn / DIM;                      // uniform per frag
    const int cc = gn - which * DIM;
    const int hh = cc >> 6, dd = cc & 63;
    const float bv = bias[gn];
#pragma unroll
    for (int mf = 0; mf < 4; ++mf) {
      const int gm0 = row0 + wm * 64 + mf * 16 + (q << 2);  // token base (x4)
      const int b = gm0 >> 11, n0 = gm0 & 2047;
      if (which == 2) {
        short4v pv;
#pragma unroll
        for (int r = 0; r < 4; ++r) pv[r] = f2bf(acc[mf][nf][r] + bv);
        *(short4v*)&vb[((size_t)(b * NH + hh) * HD + dd) * SEQ + n0] = pv;
      } else {
        bf16* dst = (which == 0) ? qb : kb;
        const float sc = (which == 0) ? SCALE_QL2E : 1.0f;
#pragma unroll
        for (int r = 0; r < 4; ++r)
          dst[((size_t)(b * NH + hh) * SEQ + n0 + r) * HD + dd] =
              __float2bfloat16((acc[mf][nf][r] + bv) * sc);
      }
    }
  }
}

// ---------------------------------------------------------------------------
// Kernel 2: flash attention — r11 T15 pipeline VERBATIM (measured best:
// 62.3 us).  Ring-3 DMA, one barrier/iter, S(kt) | PV(kt-1) | STG(kt+1) |
// softmax(kt) interleave, static pfA/pfB.  Frozen.
// ---------------------------------------------------------------------------
#define STG_KV(bb, k1)                                                        \
  async_copy16(Kb + (size_t)((k1) + drow) * HD + skey,       &KV[bb][t * 8]); \
  async_copy16(Kb + (size_t)((k1) + 32 + drow) * HD + skey,  &KV[bb][2048 + t * 8]); \
  async_copy16(Vb + (size_t)drow * SEQ + (k1) + skey,        &KV[bb][4096 + t * 8]); \
  async_copy16(Vb + (size_t)(32 + drow) * SEQ + (k1) + skey, &KV[bb][6144 + t * 8])

#define S_STEP(BK_) {                                                         \
  const short* Bf_ = KV[BK_];                                                 \
  __builtin_amdgcn_s_setprio(1);                                              \
  _Pragma("unroll") for (int jn = 0; jn < 4; ++jn) {                          \
    bf16x8 kf[2];                                                             \
    _Pragma("unroll") for (int kq = 0; kq < 2; ++kq)                          \
      kf[kq] = *(const bf16x8*)&Bf_[(jn * 16 + lr) * 64 +                     \
                                    (((kq * 32) + (q << 3)) ^ key8)];         \
    _Pragma("unroll") for (int it = 0; it < 2; ++it)                          \
    _Pragma("unroll") for (int kq = 0; kq < 2; ++kq)                          \
      s[jn][it] = __builtin_amdgcn_mfma_f32_16x16x32_bf16(kf[kq],             \
                      qf[it][kq], s[jn][it], 0, 0, 0);                        \
  }                                                                           \
  __builtin_amdgcn_s_setprio(0); }

#define PV_STEP(PF_, BP_) {                                                   \
  const short* Bv_ = KV[BP_] + 4096;                                          \
  __builtin_amdgcn_s_setprio(1);                                              \
  _Pragma("unroll") for (int c4 = 0; c4 < 2; ++c4) {                          \
    _Pragma("unroll") for (int dj = 0; dj < 4; ++dj) {                        \
      frag8 vf;                                                               \
      vf.h[0] = *(const short4v*)&Bv_[(dj * 16 + lr) * 64 +                   \
                                      ((c4 * 32 + (q << 2)) ^ key8)];         \
      vf.h[1] = *(const short4v*)&Bv_[(dj * 16 + lr) * 64 +                   \
                                      ((c4 * 32 + 16 + (q << 2)) ^ key8)];    \
      _Pragma("unroll") for (int it = 0; it < 2; ++it)                        \
        o[it][dj] = __builtin_amdgcn_mfma_f32_16x16x32_bf16(PF_[c4][it].b,    \
                        vf.b, o[it][dj], 0, 0, 0);                            \
    }                                                                         \
    _Pragma("unroll") for (int it = 0; it < 2; ++it)                          \
      lacc[it] = __builtin_amdgcn_mfma_f32_16x16x32_bf16(PF_[c4][it].b,       \
                     ones.b, lacc[it], 0, 0, 0);                              \
  }                                                                           \
  __builtin_amdgcn_s_setprio(0); }

#define SM_STEP(PF_)                                                          \
  _Pragma("unroll") for (int it = 0; it < 2; ++it)                            \
  _Pragma("unroll") for (int c4 = 0; c4 < 2; ++c4)                            \
  _Pragma("unroll") for (int r = 0; r < 4; ++r) {                             \
    PF_[c4][it].s[r]     = f2bf(__builtin_amdgcn_exp2f(s[2 * c4][it][r]));    \
    PF_[c4][it].s[4 + r] = f2bf(__builtin_amdgcn_exp2f(s[2 * c4 + 1][it][r]));\
  }

#define FA_BODY(BK_, BP_, BN_, PFP_, PFC_, TILE1_) {                          \
  float4v s[4][2] = {};                                                       \
  S_STEP(BK_);                                                                \
  PV_STEP(PFP_, BP_);                                                         \
  STG_KV(BN_, (TILE1_) * 64);                                                 \
  SM_STEP(PFC_);                                                              \
  VW0; BARRIER; }

__global__ void __launch_bounds__(256, 3)
flash_attn(const bf16* __restrict__ Qp, const bf16* __restrict__ Kp,
           const bf16* __restrict__ Vtp, bf16* __restrict__ Op) {
  const int bh = blockIdx.y, qt = blockIdx.x;
  const int t = threadIdx.x, w = t >> 6, l = t & 63, lr = l & 15, q = l >> 4;
  __shared__ short KV[3][8192];   // ring-3: {K[64][64] | V^T[64][64]}, 48 KB

  const bf16* Qb = Qp  + (size_t)(bh * SEQ + qt * 128) * HD;
  const bf16* Kb = Kp  + (size_t)bh * SEQ * HD;
  const bf16* Vb = Vtp + (size_t)bh * HD * SEQ;   // [d][n]

  // DMA coords: thread t -> dest row t>>3, 16B-slot t&7 (linear);
  // source col carries the inverse swizzle (involution)
  const int drow = t >> 3;
  const int skey = (((t & 7) ^ drow) & 7) * 8;

  // Q fragments straight from global (once per kernel)
  bf16x8 qf[2][2];
#pragma unroll
  for (int it = 0; it < 2; ++it)
#pragma unroll
    for (int kq = 0; kq < 2; ++kq)
      qf[it][kq] = *(const bf16x8*)(Qb + (size_t)(w * 32 + it * 16 + lr) * HD +
                                    kq * 32 + q * 8);

  // read-side swizzle key: all frag rows have (row&7) == (lr&7)
  const int key8 = (lr & 7) << 3;

  frag8 ones;            // all-ones bf16 B-fragment for the l row-sum MFMA
#pragma unroll
  for (int r = 0; r < 8; ++r) ones.s[r] = (short)0x3F80;

  float4v o[2][4] = {};
  float4v lacc[2] = {};  // l, col-replicated in C/D layout
  frag8 pfA[2][2], pfB[2][2];

  // prologue: tile 0 -> buf 0, drain, barrier
  STG_KV(0, 0);
  VW0; BARRIER;

  // iter 0: S(0), no PV, stage tile 1, softmax(0)->pfA
  {
    float4v s[4][2] = {};
    S_STEP(0);
    STG_KV(1, 64);
    SM_STEP(pfA);
    VW0; BARRIER;
  }

  // steady pairs kt = 1..30 (pf parity: even softmax->pfA, odd->pfB)
  int bK = 1;                        // buf of tile kt at pair top (kt%3)
#pragma unroll 1
  for (int kt = 1; kt < 31; kt += 2) {
    const int bP = (bK == 0) ? 2 : bK - 1;
    const int bN = (bK == 2) ? 0 : bK + 1;
    FA_BODY(bK, bP, bN, pfA, pfB, kt + 1)   // kt (odd):  PV(kt-1)=pfA -> pfB
    FA_BODY(bN, bK, bP, pfB, pfA, kt + 2)   // kt+1(even):PV(kt)=pfB  -> pfA
    bK = bP;                                // advance +2 mod 3
  }

  // kt = 31 (buf 1): S(31), PV(30)=pfA (buf 0), softmax(31)->pfB,
  // then drain the pipeline: PV(31)=pfB (V[31] in buf 1)
  {
    float4v s[4][2] = {};
    S_STEP(1);
    PV_STEP(pfA, 0);
    SM_STEP(pfB);
    PV_STEP(pfB, 1);
  }

  // epilogue: linv directly per lane (lacc col-replicated), no shuffles
  const int b = bh / NH, h = bh - b * NH;
#pragma unroll
  for (int it = 0; it < 2; ++it)
#pragma unroll
    for (int r = 0; r < 4; ++r) {
      const float linv = 1.0f / lacc[it][r];
      const int grow = b * SEQ + qt * 128 + w * 32 + it * 16 + (q << 2) + r;
      bf16* orow = Op + (size_t)grow * DIM + h * HD;
#pragma unroll
      for (int dj = 0; dj < 4; ++dj)
        orow[dj * 16 + lr] = __float2bfloat16(o[it][dj][r] * linv);
    }
}

// ---------------------------------------------------------------------------
// Kernel 3: output projection — r12 REWRITE (the invisible 190-TF kernel).
// r11 accounting: proj ~50-55 us on 9.7 GFLOP with the original m97 128x128
// 2-barrier structure and a 384-block grid (1.5-round makespan).  Port the
// session's measured-best GEMM structure (r6 qkv): tile 64x192, grid
// 128x4 = 512 blocks = 2 blocks/CU (one round), dbuf-2 (32 KB), BK=32
// phases, DMA staging, source-side XOR swizzle.  Wave grid 2M x 2N: wave =
// 32 rows x 96 cols = 2x6 frags, 12 MFMA/phase, acc[2][6] = 48 VGPR.
// All staging chunk row-offsets (64, 128) are 0 mod 8 -> key(row)=key(lr)
// invariant holds (same derivation as qkv).
// ---------------------------------------------------------------------------
#define PRJ_STG(s, p)                                                         \
  async_copy16(pa + (p) * 32,             &Asp[s][t * 8]);                    \
  async_copy16(pb + (p) * 32,             &Bsp[s][t * 8]);                    \
  async_copy16(pb + 64 * DIM + (p) * 32,  &Bsp[s][2048 + t * 8]);             \
  async_copy16(pb + 128 * DIM + (p) * 32, &Bsp[s][4096 + t * 8])

#define PRJ_PHASE(CUR, STG_, VW_) {                                           \
  bf16x8 af[2], bfv[6];                                                       \
  _Pragma("unroll") for (int mf_ = 0; mf_ < 2; ++mf_)                         \
    af[mf_] = *(const bf16x8*)&Asp[CUR][mf_ * 512 + arow];                    \
  _Pragma("unroll") for (int nf_ = 0; nf_ < 6; ++nf_)                         \
    bfv[nf_] = *(const bf16x8*)&Bsp[CUR][nf_ * 512 + brow];                   \
  STG_; BARRIER; LGKM0;                                                       \
  __builtin_amdgcn_s_setprio(1);                                              \
  _Pragma("unroll") for (int mf_ = 0; mf_ < 2; ++mf_)                         \
  _Pragma("unroll") for (int nf_ = 0; nf_ < 6; ++nf_)                         \
    acc[mf_][nf_] = __builtin_amdgcn_mfma_f32_16x16x32_bf16(                  \
        af[mf_], bfv[nf_], acc[mf_][nf_], 0, 0, 0);                           \
  __builtin_amdgcn_s_setprio(0); VW_; BARRIER; }

__global__ void __launch_bounds__(256, 2)
gemm_proj(const bf16* __restrict__ A, const bf16* __restrict__ W,
          const float* __restrict__ bias, float* __restrict__ out) {
  __shared__ short Asp[2][64 * 32];    // 2 x 4 KB
  __shared__ short Bsp[2][192 * 32];   // 2 x 12 KB  (total 32 KB, 2+ blk/CU)
  const int t = threadIdx.x;
  const int w = t >> 6, l = t & 63, lr = l & 15, q = l >> 4;
  const int wm = w >> 1, wn = w & 1;           // 2M x 2N wave grid

  // XCD-aware bijective swizzle: 512 blocks, 64/XCD
  const int orig = blockIdx.x;
  const int swz = (orig & 7) * 64 + (orig >> 3);
  const int tm = swz >> 2, tn = swz & 3;       // 128 row-tiles x 4 col-tiles
  const int row0 = tm * 64, col0 = tn * 192;

  const int sr = t >> 2;
  const int scol = (((t & 3) << 3) ^ (((sr >> 1) & 3) << 3));
  const bf16* pa = A + (size_t)(row0 + sr) * DIM + scol;
  const bf16* pb = W + (size_t)(col0 + sr) * DIM + scol;

  const int acol = ((q << 3) ^ (((lr >> 1) & 3) << 3));
  const int arow = (wm * 32 + lr) * 32 + acol;   // + mf*512
  const int brow = (wn * 96 + lr) * 32 + acol;   // + nf*512

  float4v acc[2][6] = {};

  PRJ_STG(0, 0);
  VW0; BARRIER;

#pragma unroll 1
  for (int k = 0; k < 22; k += 2) {
    PRJ_PHASE(0, PRJ_STG(1, k + 1), VW0)
    PRJ_PHASE(1, PRJ_STG(0, k + 2), VW0)
  }
  PRJ_PHASE(0, PRJ_STG(1, 23), VW0)   // k=22
  PRJ_PHASE(1, NOSTG,          NOVW)  // k=23

  // C-write: rows row0 + wm*32 + mf*16 + q*4 + r; cols col0 + wn*96 + nf*16 + lr
#pragma unroll
  for (int nf = 0; nf < 6; ++nf) {
    const int gn = col0 + wn * 96 + nf * 16 + lr;
    const float bv = bias[gn];
#pragma unroll
    for (int mf = 0; mf < 2; ++mf) {
#pragma unroll
      for (int r = 0; r < 4; ++r) {
        const int gm = row0 + wm * 32 + mf * 16 + (q << 2) + r;
        out[(size_t)gm * DIM + gn] = acc[mf][nf][r] + bv;
      }
    }
  }
}

// ---------------------------------------------------------------------------
extern "C" void kernel_launch(void* const* d_in, const int* in_sizes, int n_in,
                              void* d_out, int out_size, void* d_ws, size_t ws_size,
                              hipStream_t stream) {
  const float* x      = (const float*)d_in[0];
  const float* w_qkv  = (const float*)d_in[1];
  const float* b_qkv  = (const float*)d_in[2];
  const float* w_proj = (const float*)d_in[3];
  const float* b_proj = (const float*)d_in[4];
  float* out = (float*)d_out;

  const size_t perbuf = (size_t)BATCH * NH * SEQ * HD;  // 6291456 elems
  bf16* qb  = (bf16*)d_ws;
  bf16* kb  = qb + perbuf;
  bf16* vb  = kb + perbuf;          // [B,H,64,N] transposed
  bf16* ao  = vb + perbuf;
  bf16* xb  = ao + perbuf;          // NX
  bf16* wqb = xb + (size_t)NX;      // NWQ
  bf16* wpb = wqb + (size_t)NWQ;    // NWP

  const int cvt_blocks = (NX + NWQ + NWP) / 8 / 256;   // 4224
  cvt3<<<cvt_blocks, 256, 0, stream>>>(x, xb, NX, w_qkv, wqb, NWQ, w_proj, wpb, NWP);
  gemm_qkv <<<dim3(512), 256, 0, stream>>>(xb, wqb, b_qkv, qb, kb, vb);
  flash_attn<<<dim3(SEQ / 128, BATCH * NH), 256, 0, stream>>>(qb, kb, vb, ao);
  gemm_proj <<<dim3(512), 256, 0, stream>>>(ao, wpb, b_proj, out);
}